// Round 1
// baseline (1293.104 us; speedup 1.0000x reference)
//
#include <hip/hip_runtime.h>
#include <math.h>

#define NBATCH 4
#define LL 256
#define AT 14
#define FEATD 128
#define ABD 196      // AT*AT
#define NAA 484      // 22*22
#define NREL 65

// workspace layout (float offsets)
#define WS_SP   0
#define WS_TAA  (NAA*ABD)              // 94864
#define WS_TREL (WS_TAA + NAA*FEATD)   // 156816
// total = 165136 floats = 660544 bytes

#define BM 64
#define CHUNK 28
#define NCHUNK 7

struct F3 { float x, y, z; };
__device__ __forceinline__ F3 f3sub(F3 a, F3 b){ return {a.x-b.x, a.y-b.y, a.z-b.z}; }
__device__ __forceinline__ F3 f3cross(F3 a, F3 b){
    return {a.y*b.z - a.z*b.y, a.z*b.x - a.x*b.z, a.x*b.y - a.y*b.x};
}
__device__ __forceinline__ float f3dot(F3 a, F3 b){ return a.x*b.x + a.y*b.y + a.z*b.z; }

__device__ __forceinline__ float dihedral_f(F3 p0, F3 p1, F3 p2, F3 p3) {
    F3 v0 = f3sub(p2, p1);
    F3 v1 = f3sub(p0, p1);
    F3 v2 = f3sub(p3, p2);
    F3 u1 = f3cross(v0, v1);
    F3 u2 = f3cross(v0, v2);
    float q1 = f3dot(u1, u1), q2 = f3dot(u2, u2);
    float co = f3dot(u1, u2) / sqrtf(q1 * q2);
    co = fminf(fmaxf(co, -0.999999f), 0.999999f);
    float s = f3dot(f3cross(v1, v2), v0);
    float sg = (s > 0.f) ? 1.f : ((s < 0.f) ? -1.f : 0.f);
    float d = sg * acosf(co);
    if (q1 == 0.f || q2 == 0.f || !isfinite(d)) d = 0.f;  // nan_to_num
    return d;
}

// ---------------- prep kernels ----------------

__global__ void prep_sp(const float* __restrict__ dc, float* __restrict__ ws) {
    int idx = blockIdx.x * 256 + threadIdx.x;
    if (idx < NAA * ABD) {
        float v = dc[idx];
        ws[WS_SP + idx] = (v > 20.f) ? v : log1pf(expf(v));
    }
}

// T_aa[r] = aa_pair_embed[r] @ out_w1[0:128] + out_b1 ;  T_rel[r] = relpos_embed[r] @ out_w1[128:256]
__global__ void prep_tab(const float* __restrict__ aa_emb, const float* __restrict__ rel_emb,
                         const float* __restrict__ w1, const float* __restrict__ b1,
                         float* __restrict__ ws) {
    int r = blockIdx.x;
    int t = threadIdx.x;
    if (r < NAA) {
        float acc = b1[t];
        for (int k = 0; k < FEATD; k++) acc += aa_emb[r*FEATD + k] * w1[k*FEATD + t];
        ws[WS_TAA + r*FEATD + t] = acc;
    } else {
        int rr = r - NAA;
        float acc = 0.f;
        for (int k = 0; k < FEATD; k++) acc += rel_emb[rr*FEATD + k] * w1[(FEATD + k)*FEATD + t];
        ws[WS_TREL + rr*FEATD + t] = acc;
    }
}

// ---------------- main kernel ----------------

__device__ __forceinline__ void gemm_k(const float* __restrict__ Alds, int lda,
                                       const float* __restrict__ B,
                                       int K, float acc[8][4], int r0, int c0) {
    for (int k0 = 0; k0 < K; k0 += 4) {
        float4 b0 = *(const float4*)(B + (k0+0)*FEATD + c0);
        float4 b1 = *(const float4*)(B + (k0+1)*FEATD + c0);
        float4 b2 = *(const float4*)(B + (k0+2)*FEATD + c0);
        float4 b3 = *(const float4*)(B + (k0+3)*FEATD + c0);
#pragma unroll
        for (int rr = 0; rr < 8; rr++) {
            float4 av = *(const float4*)(Alds + (r0+rr)*lda + k0);
            acc[rr][0] += av.x*b0.x + av.y*b1.x + av.z*b2.x + av.w*b3.x;
            acc[rr][1] += av.x*b0.y + av.y*b1.y + av.z*b2.y + av.w*b3.y;
            acc[rr][2] += av.x*b0.z + av.y*b1.z + av.z*b2.z + av.w*b3.z;
            acc[rr][3] += av.x*b0.w + av.y*b1.w + av.z*b2.w + av.w*b3.w;
        }
    }
}

__launch_bounds__(256)
__global__ void pair_main(const int* __restrict__ aa, const int* __restrict__ res_nb,
                          const int* __restrict__ chain_nb,
                          const float* __restrict__ pos, const float* __restrict__ maskA,
                          const float* __restrict__ dist_w1, const float* __restrict__ dist_b1,
                          const float* __restrict__ dist_w2, const float* __restrict__ dist_b2,
                          const float* __restrict__ out_w1,
                          const float* __restrict__ out_w2, const float* __restrict__ out_b2,
                          const float* __restrict__ out_w3, const float* __restrict__ out_b3,
                          const float* __restrict__ ws, float* __restrict__ out) {
    __shared__ __align__(16) float buf1[BM*FEATD];      // 32 KB
    __shared__ __align__(16) float buf2[BM*FEATD];      // 32 KB : posj/maskj/Achunk, later h2/h4
    __shared__ __align__(16) float sdih[BM*26];         // 6.5 KB
    __shared__ __align__(16) float sposi[AT*3];
    __shared__ float smaski[AT];
    __shared__ int   saap[BM];
    __shared__ int   srel[BM];     // -1 if different chain, else relpos+32
    __shared__ float smjca[BM];

    float* posj  = buf2;           // BM*42 = 2688 floats
    float* maskj = buf2 + 2688;    // BM*14 = 896
    float* Ach   = buf2 + 3584;    // BM*28 = 1792  (16B-aligned: 3584*4=14336)

    const int t  = threadIdx.x;
    const int bt = blockIdx.x;
    const int jt = bt & 3;
    const int i  = (bt >> 2) & 255;
    const int n  = bt >> 10;
    const int j0 = jt * BM;

    // ---- stage i-side + j-side data ----
    const float* posNI  = pos   + (size_t)((n*LL + i)*AT)*3;
    const float* maskNI = maskA + (size_t)(n*LL + i)*AT;
    if (t < AT*3) sposi[t] = posNI[t];
    if (t >= 64 && t < 64 + AT) smaski[t - 64] = maskNI[t - 64];
    const int aa_i  = aa[n*LL + i];
    const int res_i = res_nb[n*LL + i];
    const int ch_i  = chain_nb[n*LL + i];
    if (t < BM) {
        int j = j0 + t;
        saap[t] = aa_i*22 + aa[n*LL + j];
        int rp = res_i - res_nb[n*LL + j];
        rp = min(32, max(-32, rp));
        srel[t] = (ch_i == chain_nb[n*LL + j]) ? (rp + 32) : -1;
    }
    for (int e = t; e < BM*AT; e += 256) {
        int j = e / AT, b = e - j*AT;
        int gj = j0 + j;
        maskj[e] = maskA[(size_t)(n*LL + gj)*AT + b];
        const float* ps = pos + (size_t)((n*LL + gj)*AT + b)*3;
        posj[j*42 + b*3 + 0] = ps[0];
        posj[j*42 + b*3 + 1] = ps[1];
        posj[j*42 + b*3 + 2] = ps[2];
    }
    __syncthreads();

    // capture CA mask of j before buf2 gets recycled; compute dihedrals
    if (t < BM) smjca[t] = maskj[t*AT + 1];
    if (t < 2*BM) {
        int r = t >> 1, ang = t & 1;
        const float* Pi = sposi;
        const float* Pj = posj + r*42;
        F3 p0, p1, p2, p3;
        if (ang == 0) { // phi(i,j): C_i, N_j, CA_j, C_j
            p0 = {Pi[6], Pi[7], Pi[8]};
            p1 = {Pj[0], Pj[1], Pj[2]};
            p2 = {Pj[3], Pj[4], Pj[5]};
            p3 = {Pj[6], Pj[7], Pj[8]};
        } else {        // psi(i,j): N_i, CA_i, C_i, N_j
            p0 = {Pi[0], Pi[1], Pi[2]};
            p1 = {Pi[3], Pi[4], Pi[5]};
            p2 = {Pi[6], Pi[7], Pi[8]};
            p3 = {Pj[0], Pj[1], Pj[2]};
        }
        float dh = dihedral_f(p0, p1, p2, p3);
        float* o = sdih + r*26 + ang*13;
        const float F[6] = {1.f, 2.f, 3.f, 1.f, 0.5f, 1.f/3.f};
        o[0] = dh;
#pragma unroll
        for (int q = 0; q < 6; q++) {
            o[1 + q] = sinf(dh * F[q]);
            o[7 + q] = cosf(dh * F[q]);
        }
    }
    __syncthreads();

    const int tc = t & 31, tr = t >> 5;
    const int c0 = tc * 4, r0 = tr * 8;
    float acc[8][4];

    // ---- GEMM1: h1 = relu(d_gauss[64x196] @ dist_w1 + b1), K chunked by 28 ----
#pragma unroll
    for (int rr = 0; rr < 8; rr++) { acc[rr][0]=0.f; acc[rr][1]=0.f; acc[rr][2]=0.f; acc[rr][3]=0.f; }
    const float* SP = ws + WS_SP;
    for (int cc = 0; cc < NCHUNK; cc++) {
        for (int e = t; e < BM*CHUNK; e += 256) {
            int j  = e / CHUNK, kk = e - j*CHUNK;
            int ab = cc*CHUNK + kk;
            int a  = ab / AT, b = ab - a*AT;
            float dx = sposi[a*3+0] - posj[j*42 + b*3+0];
            float dy = sposi[a*3+1] - posj[j*42 + b*3+1];
            float dz = sposi[a*3+2] - posj[j*42 + b*3+2];
            float d2 = (dx*dx + dy*dy + dz*dz) * 0.01f;
            float c  = SP[saap[j]*ABD + ab];
            Ach[e] = __expf(-c * d2) * smaski[a] * maskj[j*AT + b];
        }
        __syncthreads();
        gemm_k(Ach, CHUNK, dist_w1 + cc*CHUNK*FEATD, CHUNK, acc, r0, c0);
        __syncthreads();
    }
    {
        float4 bb = *(const float4*)(dist_b1 + c0);
#pragma unroll
        for (int rr = 0; rr < 8; rr++) {
            float* o = buf1 + (r0+rr)*FEATD + c0;
            o[0] = fmaxf(acc[rr][0] + bb.x, 0.f);
            o[1] = fmaxf(acc[rr][1] + bb.y, 0.f);
            o[2] = fmaxf(acc[rr][2] + bb.z, 0.f);
            o[3] = fmaxf(acc[rr][3] + bb.w, 0.f);
        }
    }
    __syncthreads();

    // ---- GEMM2: feat_dist = relu(h1 @ dist_w2 + b2) -> buf2 ----
#pragma unroll
    for (int rr = 0; rr < 8; rr++) { acc[rr][0]=0.f; acc[rr][1]=0.f; acc[rr][2]=0.f; acc[rr][3]=0.f; }
    gemm_k(buf1, FEATD, dist_w2, FEATD, acc, r0, c0);
    {
        float4 bb = *(const float4*)(dist_b2 + c0);
#pragma unroll
        for (int rr = 0; rr < 8; rr++) {
            float* o = buf2 + (r0+rr)*FEATD + c0;
            o[0] = fmaxf(acc[rr][0] + bb.x, 0.f);
            o[1] = fmaxf(acc[rr][1] + bb.y, 0.f);
            o[2] = fmaxf(acc[rr][2] + bb.z, 0.f);
            o[3] = fmaxf(acc[rr][3] + bb.w, 0.f);
        }
    }
    __syncthreads();

    // ---- GEMM3: pre1 = relu(feat_dist @ W1c + dihed @ W1d + T_aa[aap] + T_rel[rel]) -> buf1 ----
#pragma unroll
    for (int rr = 0; rr < 8; rr++) { acc[rr][0]=0.f; acc[rr][1]=0.f; acc[rr][2]=0.f; acc[rr][3]=0.f; }
    gemm_k(buf2, FEATD, out_w1 + 256*FEATD, FEATD, acc, r0, c0);
    for (int k = 0; k < 26; k++) {
        float4 bv = *(const float4*)(out_w1 + (384 + k)*FEATD + c0);
#pragma unroll
        for (int rr = 0; rr < 8; rr++) {
            float a = sdih[(r0+rr)*26 + k];
            acc[rr][0] += a * bv.x;
            acc[rr][1] += a * bv.y;
            acc[rr][2] += a * bv.z;
            acc[rr][3] += a * bv.w;
        }
    }
    {
        const float* TAA  = ws + WS_TAA;
        const float* TREL = ws + WS_TREL;
#pragma unroll
        for (int rr = 0; rr < 8; rr++) {
            int r = r0 + rr;
            float4 ta = *(const float4*)(TAA + saap[r]*FEATD + c0);
            float4 tr4 = {0.f, 0.f, 0.f, 0.f};
            int rl = srel[r];
            if (rl >= 0) tr4 = *(const float4*)(TREL + rl*FEATD + c0);
            float* o = buf1 + r*FEATD + c0;
            o[0] = fmaxf(acc[rr][0] + ta.x + tr4.x, 0.f);
            o[1] = fmaxf(acc[rr][1] + ta.y + tr4.y, 0.f);
            o[2] = fmaxf(acc[rr][2] + ta.z + tr4.z, 0.f);
            o[3] = fmaxf(acc[rr][3] + ta.w + tr4.w, 0.f);
        }
    }
    __syncthreads();

    // ---- GEMM4: h4 = relu(pre1 @ out_w2 + b2o) -> buf2 ----
#pragma unroll
    for (int rr = 0; rr < 8; rr++) { acc[rr][0]=0.f; acc[rr][1]=0.f; acc[rr][2]=0.f; acc[rr][3]=0.f; }
    gemm_k(buf1, FEATD, out_w2, FEATD, acc, r0, c0);
    {
        float4 bb = *(const float4*)(out_b2 + c0);
#pragma unroll
        for (int rr = 0; rr < 8; rr++) {
            float* o = buf2 + (r0+rr)*FEATD + c0;
            o[0] = fmaxf(acc[rr][0] + bb.x, 0.f);
            o[1] = fmaxf(acc[rr][1] + bb.y, 0.f);
            o[2] = fmaxf(acc[rr][2] + bb.z, 0.f);
            o[3] = fmaxf(acc[rr][3] + bb.w, 0.f);
        }
    }
    __syncthreads();

    // ---- GEMM5: out = (h4 @ out_w3 + b3o) * mask_pair ----
#pragma unroll
    for (int rr = 0; rr < 8; rr++) { acc[rr][0]=0.f; acc[rr][1]=0.f; acc[rr][2]=0.f; acc[rr][3]=0.f; }
    gemm_k(buf2, FEATD, out_w3, FEATD, acc, r0, c0);
    {
        float4 bb = *(const float4*)(out_b3 + c0);
        float mi = smaski[1];  // CA mask of residue i
#pragma unroll
        for (int rr = 0; rr < 8; rr++) {
            int r = r0 + rr;
            float mp = mi * smjca[r];
            float4 o;
            o.x = (acc[rr][0] + bb.x) * mp;
            o.y = (acc[rr][1] + bb.y) * mp;
            o.z = (acc[rr][2] + bb.z) * mp;
            o.w = (acc[rr][3] + bb.w) * mp;
            size_t off = ((size_t)((n*LL + i)*LL + j0 + r))*FEATD + c0;
            *(float4*)(out + off) = o;
        }
    }
}

// ---------------- launch ----------------

extern "C" void kernel_launch(void* const* d_in, const int* in_sizes, int n_in,
                              void* d_out, int out_size, void* d_ws, size_t ws_size,
                              hipStream_t stream) {
    const int*   aa       = (const int*)d_in[0];
    const int*   res_nb   = (const int*)d_in[1];
    const int*   chain_nb = (const int*)d_in[2];
    const float* pos      = (const float*)d_in[3];
    const float* maskA    = (const float*)d_in[4];
    const float* aa_emb   = (const float*)d_in[5];
    const float* rel_emb  = (const float*)d_in[6];
    const float* distcoef = (const float*)d_in[7];
    const float* dw1      = (const float*)d_in[8];
    const float* db1      = (const float*)d_in[9];
    const float* dw2      = (const float*)d_in[10];
    const float* db2      = (const float*)d_in[11];
    const float* ow1      = (const float*)d_in[12];
    const float* ob1      = (const float*)d_in[13];
    const float* ow2      = (const float*)d_in[14];
    const float* ob2      = (const float*)d_in[15];
    const float* ow3      = (const float*)d_in[16];
    const float* ob3      = (const float*)d_in[17];
    float* ws  = (float*)d_ws;
    float* out = (float*)d_out;

    prep_sp<<<(NAA*ABD + 255)/256, 256, 0, stream>>>(distcoef, ws);
    prep_tab<<<NAA + NREL, FEATD, 0, stream>>>(aa_emb, rel_emb, ow1, ob1, ws);
    pair_main<<<NBATCH*LL*(LL/BM), 256, 0, stream>>>(aa, res_nb, chain_nb, pos, maskA,
                                                     dw1, db1, dw2, db2,
                                                     ow1, ow2, ob2, ow3, ob3, ws, out);
}

// Round 2
// 391.561 us; speedup vs baseline: 3.3024x; 3.3024x over previous
//
#include <hip/hip_runtime.h>
#include <math.h>

typedef unsigned short u16;
typedef __attribute__((ext_vector_type(4))) float f32x4;
typedef __attribute__((ext_vector_type(8))) __bf16 bf16x8;

#define NBATCH 4
#define LL 256
#define AT 14
#define ABD 196      // AT*AT
#define NAA 484
#define NREL 65

// ---- workspace layout ----
// f32 region (float offsets)
#define WS_SP   0                       // [484][196] softplus(distcoef)
#define WS_TAA  94864                   // [484][128] aa_emb@W1a + b1
#define WS_TREL 156816                  // [65][128]  rel_emb@W1b
#define WS_BF   165136                  // bf16 weights start here (float offset)
// bf16 region (ushort offsets from ws+WS_BF)
#define UW1_OFF 0        // [128][256] dist_w1^T (K pad 196->224, stride 256)
#define UW2_OFF 32768    // [128][128] dist_w2^T
#define UW3_OFF 49152    // [128][160] out_w1[256:384]^T ++ out_w1[384:410]^T (pad 26->32)
#define UW4_OFF 69632    // [128][128] out_w2^T
#define UW5_OFF 86016    // [128][128] out_w3^T

__device__ __forceinline__ u16 f2bf(float f) {
    unsigned u = __builtin_bit_cast(unsigned, f);
    u += 0x7fffu + ((u >> 16) & 1u);          // round-to-nearest-even
    return (u16)(u >> 16);
}

struct F3 { float x, y, z; };
__device__ __forceinline__ F3 f3sub(F3 a, F3 b){ return {a.x-b.x, a.y-b.y, a.z-b.z}; }
__device__ __forceinline__ F3 f3cross(F3 a, F3 b){
    return {a.y*b.z - a.z*b.y, a.z*b.x - a.x*b.z, a.x*b.y - a.y*b.x};
}
__device__ __forceinline__ float f3dot(F3 a, F3 b){ return a.x*b.x + a.y*b.y + a.z*b.z; }

__device__ __forceinline__ float dihedral_f(F3 p0, F3 p1, F3 p2, F3 p3) {
    F3 v0 = f3sub(p2, p1);
    F3 v1 = f3sub(p0, p1);
    F3 v2 = f3sub(p3, p2);
    F3 u1 = f3cross(v0, v1);
    F3 u2 = f3cross(v0, v2);
    float q1 = f3dot(u1, u1), q2 = f3dot(u2, u2);
    float co = f3dot(u1, u2) / sqrtf(q1 * q2);
    co = fminf(fmaxf(co, -0.999999f), 0.999999f);
    float s = f3dot(f3cross(v1, v2), v0);
    float sg = (s > 0.f) ? 1.f : ((s < 0.f) ? -1.f : 0.f);
    float d = sg * acosf(co);
    if (q1 == 0.f || q2 == 0.f || !isfinite(d)) d = 0.f;
    return d;
}

// ---------------- prep kernels ----------------

__global__ void prep_sp(const float* __restrict__ dc, float* __restrict__ ws) {
    int idx = blockIdx.x * 256 + threadIdx.x;
    if (idx < NAA * ABD) {
        float v = dc[idx];
        ws[WS_SP + idx] = (v > 20.f) ? v : log1pf(expf(v));
    }
}

__global__ void prep_tab(const float* __restrict__ aa_emb, const float* __restrict__ rel_emb,
                         const float* __restrict__ w1, const float* __restrict__ b1,
                         float* __restrict__ ws) {
    int r = blockIdx.x;
    int t = threadIdx.x;
    if (r < NAA) {
        float acc = b1[t];
        for (int k = 0; k < 128; k++) acc += aa_emb[r*128 + k] * w1[k*128 + t];
        ws[WS_TAA + r*128 + t] = acc;
    } else {
        int rr = r - NAA;
        float acc = 0.f;
        for (int k = 0; k < 128; k++) acc += rel_emb[rr*128 + k] * w1[(128 + k)*128 + t];
        ws[WS_TREL + rr*128 + t] = acc;
    }
}

__global__ void prep_wt(const float* __restrict__ dw1, const float* __restrict__ dw2,
                        const float* __restrict__ ow1, const float* __restrict__ ow2,
                        const float* __restrict__ ow3, float* __restrict__ ws) {
    u16* U = (u16*)(ws + WS_BF);
    int idx = blockIdx.x * 256 + threadIdx.x;
    float v; int dst;
    if (idx < 32768) {            // Wt1 [128][256]
        int c = idx >> 8, k = idx & 255;
        v = (k < ABD) ? dw1[k*128 + c] : 0.f;
        dst = UW1_OFF + idx;
    } else if (idx < 49152) {     // Wt2 [128][128]
        int j = idx - 32768; int c = j >> 7, k = j & 127;
        v = dw2[k*128 + c];
        dst = UW2_OFF + j;
    } else if (idx < 69632) {     // Wt3 [128][160]
        int j = idx - 49152; int c = j / 160, k = j - 160*c;
        v = (k < 128) ? ow1[(256 + k)*128 + c]
                      : ((k < 154) ? ow1[(384 + k - 128)*128 + c] : 0.f);
        dst = UW3_OFF + j;
    } else if (idx < 86016) {     // Wt4
        int j = idx - 69632; int c = j >> 7, k = j & 127;
        v = ow2[k*128 + c];
        dst = UW4_OFF + j;
    } else if (idx < 102400) {    // Wt5
        int j = idx - 86016; int c = j >> 7, k = j & 127;
        v = ow3[k*128 + c];
        dst = UW5_OFF + j;
    } else return;
    U[dst] = f2bf(v);
}

// ---------------- main kernel ----------------

// A-frag: lane holds A[row = rb*16 + (l&15)][k = kg*8 + 0..7] from swizzled LDS.
// B-frag: lane holds Wt[col = c0 + cb*16 + (l&15)][k = kg*8 + 0..7] from global (L2).
template<int NS>
__device__ __forceinline__ void gemm_steps(const char* Al, int rowlog, int swzm,
                                           const u16* __restrict__ Bt, int kstride,
                                           int c0, int l15, int kg,
                                           int kbA, int kbB, f32x4 acc[4][2]) {
#pragma unroll
    for (int s = 0; s < NS; s++) {
        const int koffA = 2*(kbA + s*32 + kg*8);
        bf16x8 a0, a1, a2, a3;
        {
            int row = l15;
            a0 = *(const bf16x8*)(Al + (row << rowlog) + (koffA ^ ((row & swzm) << 4)));
            row = 16 + l15;
            a1 = *(const bf16x8*)(Al + (row << rowlog) + (koffA ^ ((row & swzm) << 4)));
            row = 32 + l15;
            a2 = *(const bf16x8*)(Al + (row << rowlog) + (koffA ^ ((row & swzm) << 4)));
            row = 48 + l15;
            a3 = *(const bf16x8*)(Al + (row << rowlog) + (koffA ^ ((row & swzm) << 4)));
        }
        const u16* bp = Bt + (size_t)(c0 + l15) * kstride + (kbB + s*32 + kg*8);
        bf16x8 b0 = *(const bf16x8*)(bp);
        bf16x8 b1 = *(const bf16x8*)(bp + 16*kstride);
        acc[0][0] = __builtin_amdgcn_mfma_f32_16x16x32_bf16(a0, b0, acc[0][0], 0,0,0);
        acc[0][1] = __builtin_amdgcn_mfma_f32_16x16x32_bf16(a0, b1, acc[0][1], 0,0,0);
        acc[1][0] = __builtin_amdgcn_mfma_f32_16x16x32_bf16(a1, b0, acc[1][0], 0,0,0);
        acc[1][1] = __builtin_amdgcn_mfma_f32_16x16x32_bf16(a1, b1, acc[1][1], 0,0,0);
        acc[2][0] = __builtin_amdgcn_mfma_f32_16x16x32_bf16(a2, b0, acc[2][0], 0,0,0);
        acc[2][1] = __builtin_amdgcn_mfma_f32_16x16x32_bf16(a2, b1, acc[2][1], 0,0,0);
        acc[3][0] = __builtin_amdgcn_mfma_f32_16x16x32_bf16(a3, b0, acc[3][0], 0,0,0);
        acc[3][1] = __builtin_amdgcn_mfma_f32_16x16x32_bf16(a3, b1, acc[3][1], 0,0,0);
    }
}

#define ZACC do { _Pragma("unroll") for (int _r=0;_r<4;_r++) { \
    acc[_r][0] = f32x4{0.f,0.f,0.f,0.f}; acc[_r][1] = f32x4{0.f,0.f,0.f,0.f}; } } while(0)

__launch_bounds__(256, 2)
__global__ void pair_main(const int* __restrict__ aa, const int* __restrict__ res_nb,
                          const int* __restrict__ chain_nb,
                          const float* __restrict__ pos, const float* __restrict__ maskA,
                          const float* __restrict__ dist_b1, const float* __restrict__ dist_b2,
                          const float* __restrict__ out_b2, const float* __restrict__ out_b3,
                          const float* __restrict__ ws, float* __restrict__ out) {
    __shared__ __align__(16) u16 buf_g[64*256];   // 32 KB: gauss bf16 (stride 512B) -> later Tsum f32 [64][128]
    __shared__ __align__(16) u16 bufA[64*128];    // 16 KB: posj f32 staging -> h1 -> h3
    __shared__ __align__(16) u16 bufB[64*128];    // 16 KB: maskj f32 staging -> h2 -> h4
    __shared__ __align__(16) u16 sdih[64*32];     // 4 KB: dihedral feats bf16 (stride 64B, swz &3)
    __shared__ float sposi[42];
    __shared__ float smaski[14];
    __shared__ int   saap[64];
    __shared__ int   srel[64];
    __shared__ float smjca[64];

    const float* SP   = ws + WS_SP;
    const float* TAA  = ws + WS_TAA;
    const float* TREL = ws + WS_TREL;
    const u16*   UW   = (const u16*)(ws + WS_BF);

    const int t  = threadIdx.x;
    const int bt = blockIdx.x;
    const int jt = bt & 3, i = (bt >> 2) & 255, n = bt >> 10;
    const int j0 = jt * 64;

    const int lane = t & 63, w = t >> 6;
    const int l15 = lane & 15, lg = lane >> 4;
    const int c0w = w * 32;

    // per-lane bias preload (L2-hot)
    float db1c[2], db2c[2], ob2c[2], ob3c[2];
#pragma unroll
    for (int cb = 0; cb < 2; cb++) {
        int col = c0w + cb*16 + l15;
        db1c[cb] = dist_b1[col];
        db2c[cb] = dist_b2[col];
        ob2c[cb] = out_b2[col];
        ob3c[cb] = out_b3[col];
    }

    float* posjf  = (float*)bufA;   // [64][48] (b*3+d)
    float* maskjf = (float*)bufB;   // [64][16]

    // ---- stage i-side + j-side ----
    const float* posNI  = pos   + (size_t)((n*LL + i)*AT)*3;
    const float* maskNI = maskA + (size_t)(n*LL + i)*AT;
    if (t < 42) sposi[t] = posNI[t];
    if (t >= 64 && t < 78) smaski[t - 64] = maskNI[t - 64];
    const int aa_i = aa[n*LL + i], res_i = res_nb[n*LL + i], ch_i = chain_nb[n*LL + i];
    if (t < 64) {
        int j = j0 + t;
        saap[t] = aa_i*22 + aa[n*LL + j];
        int rp = res_i - res_nb[n*LL + j];
        rp = min(32, max(-32, rp));
        srel[t] = (ch_i == chain_nb[n*LL + j]) ? (rp + 32) : -1;
    }
    for (int e = t; e < 64*AT; e += 256) {
        int j = e / AT, b = e - j*AT;
        int gj = j0 + j;
        maskjf[j*16 + b] = maskA[(size_t)(n*LL + gj)*AT + b];
        const float* ps = pos + (size_t)((n*LL + gj)*AT + b)*3;
        posjf[j*48 + b*3 + 0] = ps[0];
        posjf[j*48 + b*3 + 1] = ps[1];
        posjf[j*48 + b*3 + 2] = ps[2];
    }
    __syncthreads();

    if (t < 64) smjca[t] = maskjf[t*16 + 1];
    if (t < 64) {   // zero-pad dihedral cols 26..31
        char* sd = (char*)sdih + t*64;
#pragma unroll
        for (int c = 26; c < 32; c++) *(u16*)(sd + ((2*c) ^ ((t & 3) << 4))) = 0;
    }
    if (t < 128) {  // dihedrals: 64 rows x {phi, psi}
        int r = t >> 1, angv = t & 1;
        const float* Pj = posjf + r*48;
        F3 p0, p1, p2, p3;
        if (angv == 0) {  // phi(i,j): C_i, N_j, CA_j, C_j
            p0 = {sposi[6], sposi[7], sposi[8]};
            p1 = {Pj[0], Pj[1], Pj[2]};
            p2 = {Pj[3], Pj[4], Pj[5]};
            p3 = {Pj[6], Pj[7], Pj[8]};
        } else {          // psi(i,j): N_i, CA_i, C_i, N_j
            p0 = {sposi[0], sposi[1], sposi[2]};
            p1 = {sposi[3], sposi[4], sposi[5]};
            p2 = {sposi[6], sposi[7], sposi[8]};
            p3 = {Pj[0], Pj[1], Pj[2]};
        }
        float dh = dihedral_f(p0, p1, p2, p3);
        const float F[6] = {1.f, 2.f, 3.f, 1.f, 0.5f, 1.f/3.f};
        char* sd = (char*)sdih + r*64;
        int cb0 = angv * 13;
        *(u16*)(sd + ((2*cb0) ^ ((r & 3) << 4))) = f2bf(dh);
#pragma unroll
        for (int q = 0; q < 6; q++) {
            *(u16*)(sd + ((2*(cb0+1+q)) ^ ((r & 3) << 4))) = f2bf(sinf(dh * F[q]));
            *(u16*)(sd + ((2*(cb0+7+q)) ^ ((r & 3) << 4))) = f2bf(cosf(dh * F[q]));
        }
    }
    // ---- gauss features -> buf_g bf16 [64][224 used, stride 256] swizzled ----
    for (int q = t; q < 3584; q += 256) {
        int r = q / 56, kq = (q - r*56) * 4;
        int sa = saap[r];
        ushort4 pk;
#pragma unroll
        for (int u = 0; u < 4; u++) {
            int k = kq + u;
            float g = 0.f;
            if (k < ABD) {
                int a_ = k / 14, b_ = k - a_*14;
                float dx = sposi[a_*3+0] - posjf[r*48 + b_*3+0];
                float dy = sposi[a_*3+1] - posjf[r*48 + b_*3+1];
                float dz = sposi[a_*3+2] - posjf[r*48 + b_*3+2];
                float d2 = (dx*dx + dy*dy + dz*dz) * 0.01f;
                float c = SP[sa*ABD + k];
                g = __expf(-c * d2) * smaski[a_] * maskjf[r*16 + b_];
            }
            ((u16*)&pk)[u] = f2bf(g);
        }
        *(ushort4*)((char*)buf_g + r*512 + ((2*kq) ^ ((r & 7) << 4))) = pk;
    }
    __syncthreads();

    f32x4 acc[4][2];

    // ---- GEMM1: h1 = relu(gauss @ dist_w1 + b1) -> bufA ----
    ZACC;
    gemm_steps<7>((const char*)buf_g, 9, 7, UW + UW1_OFF, 256, c0w, l15, lg, 0, 0, acc);
#pragma unroll
    for (int rb = 0; rb < 4; rb++)
#pragma unroll
        for (int cb = 0; cb < 2; cb++)
#pragma unroll
            for (int rg = 0; rg < 4; rg++) {
                int row = rb*16 + lg*4 + rg;
                int col = c0w + cb*16 + l15;
                float v = fmaxf(acc[rb][cb][rg] + db1c[cb], 0.f);
                *(u16*)((char*)bufA + row*256 + ((2*col) ^ ((row & 7) << 4))) = f2bf(v);
            }
    __syncthreads();

    // ---- GEMM2: h2 = relu(h1 @ dist_w2 + b2) -> bufB ; stage Tsum f32 into buf_g ----
    ZACC;
    for (int q = t; q < 2048; q += 256) {
        int r = q >> 5, c4 = (q & 31) * 4;
        float4 v = *(const float4*)(TAA + saap[r]*128 + c4);
        if (srel[r] >= 0) {
            float4 u2 = *(const float4*)(TREL + srel[r]*128 + c4);
            v.x += u2.x; v.y += u2.y; v.z += u2.z; v.w += u2.w;
        }
        *(float4*)((char*)buf_g + r*512 + ((4*c4) ^ ((r & 7) << 4))) = v;
    }
    gemm_steps<4>((const char*)bufA, 8, 7, UW + UW2_OFF, 128, c0w, l15, lg, 0, 0, acc);
#pragma unroll
    for (int rb = 0; rb < 4; rb++)
#pragma unroll
        for (int cb = 0; cb < 2; cb++)
#pragma unroll
            for (int rg = 0; rg < 4; rg++) {
                int row = rb*16 + lg*4 + rg;
                int col = c0w + cb*16 + l15;
                float v = fmaxf(acc[rb][cb][rg] + db2c[cb], 0.f);
                *(u16*)((char*)bufB + row*256 + ((2*col) ^ ((row & 7) << 4))) = f2bf(v);
            }
    __syncthreads();

    // ---- GEMM3: h3 = relu(h2 @ W1c + dihed @ W1d + Tsum) -> bufA ----
    ZACC;
    gemm_steps<4>((const char*)bufB, 8, 7, UW + UW3_OFF, 160, c0w, l15, lg, 0, 0, acc);
    gemm_steps<1>((const char*)sdih, 6, 3, UW + UW3_OFF, 160, c0w, l15, lg, 0, 128, acc);
#pragma unroll
    for (int rb = 0; rb < 4; rb++)
#pragma unroll
        for (int cb = 0; cb < 2; cb++)
#pragma unroll
            for (int rg = 0; rg < 4; rg++) {
                int row = rb*16 + lg*4 + rg;
                int col = c0w + cb*16 + l15;
                float ts = *(const float*)((char*)buf_g + row*512 + ((4*col) ^ ((row & 7) << 4)));
                float v = fmaxf(acc[rb][cb][rg] + ts, 0.f);
                *(u16*)((char*)bufA + row*256 + ((2*col) ^ ((row & 7) << 4))) = f2bf(v);
            }
    __syncthreads();

    // ---- GEMM4: h4 = relu(h3 @ out_w2 + ob2) -> bufB ----
    ZACC;
    gemm_steps<4>((const char*)bufA, 8, 7, UW + UW4_OFF, 128, c0w, l15, lg, 0, 0, acc);
#pragma unroll
    for (int rb = 0; rb < 4; rb++)
#pragma unroll
        for (int cb = 0; cb < 2; cb++)
#pragma unroll
            for (int rg = 0; rg < 4; rg++) {
                int row = rb*16 + lg*4 + rg;
                int col = c0w + cb*16 + l15;
                float v = fmaxf(acc[rb][cb][rg] + ob2c[cb], 0.f);
                *(u16*)((char*)bufB + row*256 + ((2*col) ^ ((row & 7) << 4))) = f2bf(v);
            }
    __syncthreads();

    // ---- GEMM5: out = (h4 @ out_w3 + ob3) * mask_pair ----
    ZACC;
    gemm_steps<4>((const char*)bufB, 8, 7, UW + UW5_OFF, 128, c0w, l15, lg, 0, 0, acc);
    {
        float mi = smaski[1];
#pragma unroll
        for (int rb = 0; rb < 4; rb++)
#pragma unroll
            for (int cb = 0; cb < 2; cb++)
#pragma unroll
                for (int rg = 0; rg < 4; rg++) {
                    int row = rb*16 + lg*4 + rg;
                    int col = c0w + cb*16 + l15;
                    float mp = mi * smjca[row];
                    out[((size_t)(n*LL + i)*LL + j0 + row)*128 + col] =
                        (acc[rb][cb][rg] + ob3c[cb]) * mp;
                }
    }
}

// ---------------- launch ----------------

extern "C" void kernel_launch(void* const* d_in, const int* in_sizes, int n_in,
                              void* d_out, int out_size, void* d_ws, size_t ws_size,
                              hipStream_t stream) {
    const int*   aa       = (const int*)d_in[0];
    const int*   res_nb   = (const int*)d_in[1];
    const int*   chain_nb = (const int*)d_in[2];
    const float* pos      = (const float*)d_in[3];
    const float* maskA    = (const float*)d_in[4];
    const float* aa_emb   = (const float*)d_in[5];
    const float* rel_emb  = (const float*)d_in[6];
    const float* distcoef = (const float*)d_in[7];
    const float* dw1      = (const float*)d_in[8];
    const float* db1      = (const float*)d_in[9];
    const float* dw2      = (const float*)d_in[10];
    const float* db2      = (const float*)d_in[11];
    const float* ow1      = (const float*)d_in[12];
    const float* ob1      = (const float*)d_in[13];
    const float* ow2      = (const float*)d_in[14];
    const float* ob2      = (const float*)d_in[15];
    const float* ow3      = (const float*)d_in[16];
    const float* ob3      = (const float*)d_in[17];
    float* ws  = (float*)d_ws;
    float* out = (float*)d_out;

    prep_sp<<<(NAA*ABD + 255)/256, 256, 0, stream>>>(distcoef, ws);
    prep_tab<<<NAA + NREL, 128, 0, stream>>>(aa_emb, rel_emb, ow1, ob1, ws);
    prep_wt<<<400, 256, 0, stream>>>(dw1, dw2, ow1, ow2, ow3, ws);
    pair_main<<<NBATCH*LL*4, 256, 0, stream>>>(aa, res_nb, chain_nb, pos, maskA,
                                               db1, db2, ob2, ob3, ws, out);
}

// Round 8
// 385.919 us; speedup vs baseline: 3.3507x; 1.0146x over previous
//
#include <hip/hip_runtime.h>
#include <math.h>

typedef unsigned short u16;
typedef __attribute__((ext_vector_type(4))) float f32x4;
typedef __attribute__((ext_vector_type(8))) __bf16 bf16x8;

#define NBATCH 4
#define LL 256
#define AT 14
#define ABD 196      // AT*AT
#define NAA 484

// ---- ws layout: ROUND-2 VERBATIM (verified) ----
// f32 region (float offsets)
#define WS_SP   0                       // [484][196] softplus(distcoef)
#define WS_TAA  94864                   // [484][128] aa_emb@W1a + b1
#define WS_TREL 156816                  // [65][128]  rel_emb@W1b
#define WS_BF   165136                  // bf16 weights (u16 region), 102400 u16
// u16 offsets within UW:
#define UW1 0        // [128 c'][256 k] dist_w1^T (k = a*14+b, pad 196->256 zeros)
#define UW2 32768    // [128][128] dist_w2^T
#define UW3 49152    // [128][160] out_w1[256:384]^T ++ out_w1[384:410]^T (pad->160)
#define UW4 69632    // [128][128] out_w2^T
#define UW5 86016    // [128][128] out_w3^T

__device__ __forceinline__ u16 f2bf(float f) {
    unsigned u = __builtin_bit_cast(unsigned, f);
    u += 0x7fffu + ((u >> 16) & 1u);          // RNE
    return (u16)(u >> 16);
}

struct F3 { float x, y, z; };
__device__ __forceinline__ F3 f3sub(F3 a, F3 b){ return {a.x-b.x, a.y-b.y, a.z-b.z}; }
__device__ __forceinline__ F3 f3cross(F3 a, F3 b){
    return {a.y*b.z - a.z*b.y, a.z*b.x - a.x*b.z, a.x*b.y - a.y*b.x};
}
__device__ __forceinline__ float f3dot(F3 a, F3 b){ return a.x*b.x + a.y*b.y + a.z*b.z; }

__device__ __forceinline__ float dihedral_f(F3 p0, F3 p1, F3 p2, F3 p3) {
    F3 v0 = f3sub(p2, p1);
    F3 v1 = f3sub(p0, p1);
    F3 v2 = f3sub(p3, p2);
    F3 u1 = f3cross(v0, v1);
    F3 u2 = f3cross(v0, v2);
    float q1 = f3dot(u1, u1), q2 = f3dot(u2, u2);
    float co = f3dot(u1, u2) / sqrtf(q1 * q2);
    co = fminf(fmaxf(co, -0.999999f), 0.999999f);
    float s = f3dot(f3cross(v1, v2), v0);
    float sg = (s > 0.f) ? 1.f : ((s < 0.f) ? -1.f : 0.f);
    float d = sg * acosf(co);
    if (q1 == 0.f || q2 == 0.f || !isfinite(d)) d = 0.f;
    return d;
}

// ---------------- prep kernels: ROUND-2 VERBATIM (verified) ----------------

__global__ void prep_sp(const float* __restrict__ dc, float* __restrict__ ws) {
    int idx = blockIdx.x * 256 + threadIdx.x;
    if (idx < NAA * ABD) {
        float v = dc[idx];
        ws[WS_SP + idx] = (v > 20.f) ? v : log1pf(expf(v));
    }
}

__global__ void prep_tab(const float* __restrict__ aa_emb, const float* __restrict__ rel_emb,
                         const float* __restrict__ w1, const float* __restrict__ b1,
                         float* __restrict__ ws) {
    int r = blockIdx.x;
    int t = threadIdx.x;
    if (r < NAA) {
        float acc = b1[t];
        for (int k = 0; k < 128; k++) acc += aa_emb[r*128 + k] * w1[k*128 + t];
        ws[WS_TAA + r*128 + t] = acc;
    } else {
        int rr = r - NAA;
        float acc = 0.f;
        for (int k = 0; k < 128; k++) acc += rel_emb[rr*128 + k] * w1[(128 + k)*128 + t];
        ws[WS_TREL + rr*128 + t] = acc;
    }
}

__global__ void prep_wt(const float* __restrict__ dw1, const float* __restrict__ dw2,
                        const float* __restrict__ ow1, const float* __restrict__ ow2,
                        const float* __restrict__ ow3, float* __restrict__ ws) {
    u16* U = (u16*)(ws + WS_BF);
    int idx = blockIdx.x * 256 + threadIdx.x;
    float v; int dst;
    if (idx < 32768) {            // Wt1 [128][256]
        int c = idx >> 8, k = idx & 255;
        v = (k < ABD) ? dw1[k*128 + c] : 0.f;
        dst = UW1 + idx;
    } else if (idx < 49152) {     // Wt2 [128][128]
        int j = idx - 32768; int c = j >> 7, k = j & 127;
        v = dw2[k*128 + c];
        dst = UW2 + j;
    } else if (idx < 69632) {     // Wt3 [128][160]
        int j = idx - 49152; int c = j / 160, k = j - 160*c;
        v = (k < 128) ? ow1[(256 + k)*128 + c]
                      : ((k < 154) ? ow1[(384 + k - 128)*128 + c] : 0.f);
        dst = UW3 + j;
    } else if (idx < 86016) {     // Wt4
        int j = idx - 69632; int c = j >> 7, k = j & 127;
        v = ow2[k*128 + c];
        dst = UW4 + j;
    } else if (idx < 102400) {    // Wt5
        int j = idx - 86016; int c = j >> 7, k = j & 127;
        v = ow3[k*128 + c];
        dst = UW5 + j;
    } else return;
    U[dst] = f2bf(v);
}

// ---------------- main kernel ----------------
// All GEMMs computed transposed: D[c'][r] = sum_k Wt[c'][k] * act[r][k].
// A-frag = weights (global, rows c'), B-frag = activations (LDS, S[r][k] k-contiguous).
// D frag: col=r=lane&15 (fixed/lane), row=c'=lg*4+reg -> reg-quad = 4 consecutive
// features => one 8B swizzled ds_write per acc quad; output IS the next GEMM's B layout.

template<int NS, int RLOG>
__device__ __forceinline__ void gemmO(const u16* Sact, const u16* __restrict__ Wt, int kst,
                                      int kbA, int kbB, const int* r16, int bswz, int lg,
                                      int wl15, f32x4 acc[2][4]) {
    const u16* aP0 = Wt + (size_t)wl15 * kst + kbA + lg*8;
    const u16* aP1 = aP0 + (size_t)16 * kst;
    const char* Sb = (const char*)Sact;
#pragma unroll
    for (int s = 0; s < NS; s++) {
        bf16x8 af0 = *(const bf16x8*)(aP0 + s*32);
        bf16x8 af1 = *(const bf16x8*)(aP1 + s*32);
        int inrow = (((kbB + s*32)*2) + lg*16) ^ bswz;
        bf16x8 b0 = *(const bf16x8*)(Sb + (r16[0] << RLOG) + inrow);
        bf16x8 b1 = *(const bf16x8*)(Sb + (r16[1] << RLOG) + inrow);
        bf16x8 b2 = *(const bf16x8*)(Sb + (r16[2] << RLOG) + inrow);
        bf16x8 b3 = *(const bf16x8*)(Sb + (r16[3] << RLOG) + inrow);
        acc[0][0] = __builtin_amdgcn_mfma_f32_16x16x32_bf16(af0, b0, acc[0][0], 0,0,0);
        acc[0][1] = __builtin_amdgcn_mfma_f32_16x16x32_bf16(af0, b1, acc[0][1], 0,0,0);
        acc[0][2] = __builtin_amdgcn_mfma_f32_16x16x32_bf16(af0, b2, acc[0][2], 0,0,0);
        acc[0][3] = __builtin_amdgcn_mfma_f32_16x16x32_bf16(af0, b3, acc[0][3], 0,0,0);
        acc[1][0] = __builtin_amdgcn_mfma_f32_16x16x32_bf16(af1, b0, acc[1][0], 0,0,0);
        acc[1][1] = __builtin_amdgcn_mfma_f32_16x16x32_bf16(af1, b1, acc[1][1], 0,0,0);
        acc[1][2] = __builtin_amdgcn_mfma_f32_16x16x32_bf16(af1, b2, acc[1][2], 0,0,0);
        acc[1][3] = __builtin_amdgcn_mfma_f32_16x16x32_bf16(af1, b3, acc[1][3], 0,0,0);
    }
}

#define ZACC do { _Pragma("unroll") for (int _m = 0; _m < 2; _m++) \
    { acc[_m][0] = f32x4{0.f,0.f,0.f,0.f}; acc[_m][1] = f32x4{0.f,0.f,0.f,0.f}; \
      acc[_m][2] = f32x4{0.f,0.f,0.f,0.f}; acc[_m][3] = f32x4{0.f,0.f,0.f,0.f}; } } while(0)

#define EPI_WRITE(DST, RL, BV) do { \
  _Pragma("unroll") for (int mt = 0; mt < 2; mt++) { \
    float4 bb = BV[mt]; int cb2 = (cq0 + mt*16)*2; \
    _Pragma("unroll") for (int ct = 0; ct < 4; ct++) { \
      ushort4 pk; \
      pk.x = f2bf(fmaxf(acc[mt][ct][0] + bb.x, 0.f)); \
      pk.y = f2bf(fmaxf(acc[mt][ct][1] + bb.y, 0.f)); \
      pk.z = f2bf(fmaxf(acc[mt][ct][2] + bb.z, 0.f)); \
      pk.w = f2bf(fmaxf(acc[mt][ct][3] + bb.w, 0.f)); \
      *(ushort4*)((char*)(DST) + (r16[ct] << (RL)) + (cb2 ^ swz)) = pk; \
    } } } while(0)

__launch_bounds__(256, 3)
__global__ void pair_main(const int* __restrict__ aa, const int* __restrict__ res_nb,
                          const int* __restrict__ chain_nb,
                          const float* __restrict__ pos, const float* __restrict__ maskA,
                          const float* __restrict__ dist_b1, const float* __restrict__ dist_b2,
                          const float* __restrict__ out_b2, const float* __restrict__ out_b3,
                          const float* __restrict__ ws, float* __restrict__ out) {
    __shared__ __align__(16) u16 SB[64*256];  // 32 KB, 512-B rows: gauss / h2 / h4
    __shared__ __align__(16) u16 SA[64*128];  // 16 KB, 256-B rows: posj+maskj staging / h1 / h3
    __shared__ __align__(16) u16 sdih[64*32]; // 4 KB, 64-B rows: dihedral feats (round-2 layout)
    __shared__ float sposi[42];
    __shared__ float smaski[14];
    __shared__ int   saap[64];
    __shared__ int   srel[64];

    const float* SP   = ws + WS_SP;
    const float* TAA  = ws + WS_TAA;
    const float* TREL = ws + WS_TREL;
    const u16*   UW   = (const u16*)(ws + WS_BF);

    const int t  = threadIdx.x;
    const int bt = blockIdx.x;
    const int jt = bt & 3, i = (bt >> 2) & 255, n = bt >> 10;
    const int j0 = jt * 64;

    const int lane = t & 63, w = t >> 6;
    const int l15 = lane & 15, lg = lane >> 4;
    const int swz = (l15 & 7) << 4;
    const int wl15 = w*32 + l15;
    const int cq0 = w*32 + lg*4;
    int r16[4];
#pragma unroll
    for (int ct = 0; ct < 4; ct++) r16[ct] = ct*16 + l15;

    // per-lane bias preload (c'-indexed, L2-hot)
    float4 db1v[2], db2v[2], ob2v[2], ob3v[2];
#pragma unroll
    for (int mt = 0; mt < 2; mt++) {
        int cq = cq0 + mt*16;
        db1v[mt] = *(const float4*)(dist_b1 + cq);
        db2v[mt] = *(const float4*)(dist_b2 + cq);
        ob2v[mt] = *(const float4*)(out_b2 + cq);
        ob3v[mt] = *(const float4*)(out_b3 + cq);
    }

    float* posjf  = (float*)SA;           // [64][42]  (round-2 strides)
    float* maskjf = (float*)SA + 64*42;   // [64][14]

    // ---- stage (round-2 verbatim) ----
    const float* posNI  = pos   + (size_t)((n*LL + i)*AT)*3;
    const float* maskNI = maskA + (size_t)(n*LL + i)*AT;
    if (t < 42) sposi[t] = posNI[t];
    if (t >= 64 && t < 78) smaski[t - 64] = maskNI[t - 64];
    const int aa_i = aa[n*LL + i], res_i = res_nb[n*LL + i], ch_i = chain_nb[n*LL + i];
    if (t < 64) {
        int j = j0 + t;
        saap[t] = aa_i*22 + aa[n*LL + j];
        int rp = res_i - res_nb[n*LL + j];
        rp = min(32, max(-32, rp));
        srel[t] = (ch_i == chain_nb[n*LL + j]) ? (rp + 32) : -1;
    }
    for (int e = t; e < 64*AT; e += 256) {
        int j = e / AT, b = e - j*AT;
        int gj = j0 + j;
        maskjf[e] = maskA[(size_t)(n*LL + gj)*AT + b];
        const float* ps = pos + (size_t)((n*LL + gj)*AT + b)*3;
        posjf[j*42 + b*3 + 0] = ps[0];
        posjf[j*42 + b*3 + 1] = ps[1];
        posjf[j*42 + b*3 + 2] = ps[2];
    }
    __syncthreads();   // B0

    // per-lane r-indexed preloads (valid until GEMM1 epilogue clobbers SA)
    int saR[4], srR[4]; float mjR[4];
#pragma unroll
    for (int ct = 0; ct < 4; ct++) {
        saR[ct] = saap[r16[ct]];
        srR[ct] = srel[r16[ct]];
        mjR[ct] = maskjf[r16[ct]*AT + 1];
    }
    const float mi = smaski[1];

    // ---- gauss features -> SB cols 0..223 (ROUND-2 VERBATIM loop) ----
    for (int q = t; q < 3584; q += 256) {
        int r = q / 56, kq = (q - r*56) * 4;
        int sa = saap[r];
        ushort4 pk;
#pragma unroll
        for (int u = 0; u < 4; u++) {
            int k = kq + u;
            float g = 0.f;
            if (k < ABD) {
                int a_ = k / 14, b_ = k - a_*14;
                float dx = sposi[a_*3+0] - posjf[r*42 + b_*3+0];
                float dy = sposi[a_*3+1] - posjf[r*42 + b_*3+1];
                float dz = sposi[a_*3+2] - posjf[r*42 + b_*3+2];
                float d2 = (dx*dx + dy*dy + dz*dz) * 0.01f;
                float c = SP[sa*ABD + k];
                g = __expf(-c * d2) * smaski[a_] * maskjf[r*AT + b_];
            }
            ((u16*)&pk)[u] = f2bf(g);
        }
        *(ushort4*)((char*)SB + r*512 + ((2*kq) ^ ((r & 7) << 4))) = pk;
    }

    // ---- dihedral feats -> sdih (ROUND-2 VERBATIM: 64-B rows, swz (r&3)<<4) ----
    if (t < 64) {   // zero-pad cols 26..31
        char* sd = (char*)sdih + t*64;
#pragma unroll
        for (int c = 26; c < 32; c++) *(u16*)(sd + ((2*c) ^ ((t & 3) << 4))) = 0;
    }
    if (t < 128) {
        int r = t >> 1, angv = t & 1;
        const float* Pj = posjf + r*42;
        F3 p0, p1, p2, p3;
        if (angv == 0) {  // phi(i,j): C_i, N_j, CA_j, C_j
            p0 = {sposi[6], sposi[7], sposi[8]};
            p1 = {Pj[0], Pj[1], Pj[2]};
            p2 = {Pj[3], Pj[4], Pj[5]};
            p3 = {Pj[6], Pj[7], Pj[8]};
        } else {          // psi(i,j): N_i, CA_i, C_i, N_j
            p0 = {sposi[0], sposi[1], sposi[2]};
            p1 = {sposi[3], sposi[4], sposi[5]};
            p2 = {sposi[6], sposi[7], sposi[8]};
            p3 = {Pj[0], Pj[1], Pj[2]};
        }
        float dh = dihedral_f(p0, p1, p2, p3);
        char* sd = (char*)sdih + r*64;
        int szd = (r & 3) << 4;
        int cb0 = angv * 13;
        const float F[6] = {1.f, 2.f, 3.f, 1.f, 0.5f, 1.f/3.f};
        *(u16*)(sd + ((2*cb0) ^ szd)) = f2bf(dh);
#pragma unroll
        for (int q = 0; q < 6; q++) {
            *(u16*)(sd + ((2*(cb0+1+q)) ^ szd)) = f2bf(sinf(dh * F[q]));
            *(u16*)(sd + ((2*(cb0+7+q)) ^ szd)) = f2bf(cosf(dh * F[q]));
        }
    }
    __syncthreads();   // B1

    f32x4 acc[2][4];

    // ---- GEMM1: h1 = relu(gauss @ dist_w1 + b1) -> SA ----
    ZACC;
    gemmO<7,9>((const u16*)SB, UW + UW1, 256, 0, 0, r16, swz, lg, wl15, acc);
    EPI_WRITE(SA, 8, db1v);
    __syncthreads();   // B2

    // ---- GEMM2: h2 = relu(h1 @ dist_w2 + b2) -> SB cols 0..127 ----
    ZACC;
    gemmO<4,8>((const u16*)SA, UW + UW2, 128, 0, 0, r16, swz, lg, wl15, acc);
    EPI_WRITE(SB, 9, db2v);
    __syncthreads();   // B3

    // ---- GEMM3: h3 = relu(h2 @ W1c + dihed @ W1d + T_aa + T_rel) -> SA ----
    ZACC;
    gemmO<4,9>((const u16*)SB, UW + UW3, 160, 0, 0, r16, swz, lg, wl15, acc);
    gemmO<1,6>(sdih, UW + UW3, 160, 128, 0, r16, (l15 & 3) << 4, lg, wl15, acc);
#pragma unroll
    for (int mt = 0; mt < 2; mt++) {
        int cq = cq0 + mt*16; int cb2 = cq*2;
#pragma unroll
        for (int ct = 0; ct < 4; ct++) {
            float4 tv = *(const float4*)(TAA + (size_t)saR[ct]*128 + cq);
            if (srR[ct] >= 0) {
                float4 u2 = *(const float4*)(TREL + (size_t)srR[ct]*128 + cq);
                tv.x += u2.x; tv.y += u2.y; tv.z += u2.z; tv.w += u2.w;
            }
            ushort4 pk;
            pk.x = f2bf(fmaxf(acc[mt][ct][0] + tv.x, 0.f));
            pk.y = f2bf(fmaxf(acc[mt][ct][1] + tv.y, 0.f));
            pk.z = f2bf(fmaxf(acc[mt][ct][2] + tv.z, 0.f));
            pk.w = f2bf(fmaxf(acc[mt][ct][3] + tv.w, 0.f));
            *(ushort4*)((char*)SA + (r16[ct] << 8) + (cb2 ^ swz)) = pk;
        }
    }
    __syncthreads();   // B4

    // ---- GEMM4: h4 = relu(h3 @ out_w2 + ob2) -> SB ----
    ZACC;
    gemmO<4,8>((const u16*)SA, UW + UW4, 128, 0, 0, r16, swz, lg, wl15, acc);
    EPI_WRITE(SB, 9, ob2v);
    __syncthreads();   // B5

    // ---- GEMM5: out = (h4 @ out_w3 + ob3) * mask_pair ----
    ZACC;
    gemmO<4,9>((const u16*)SB, UW + UW5, 128, 0, 0, r16, swz, lg, wl15, acc);
#pragma unroll
    for (int mt = 0; mt < 2; mt++) {
        int cq = cq0 + mt*16;
        float4 bb = ob3v[mt];
#pragma unroll
        for (int ct = 0; ct < 4; ct++) {
            float mp = mi * mjR[ct];
            float4 v;
            v.x = (acc[mt][ct][0] + bb.x) * mp;
            v.y = (acc[mt][ct][1] + bb.y) * mp;
            v.z = (acc[mt][ct][2] + bb.z) * mp;
            v.w = (acc[mt][ct][3] + bb.w) * mp;
            *(float4*)(out + ((size_t)((n*LL + i)*LL) + j0 + r16[ct]) * 128 + cq) = v;
        }
    }
}

// ---------------- launch ----------------

extern "C" void kernel_launch(void* const* d_in, const int* in_sizes, int n_in,
                              void* d_out, int out_size, void* d_ws, size_t ws_size,
                              hipStream_t stream) {
    const int*   aa       = (const int*)d_in[0];
    const int*   res_nb   = (const int*)d_in[1];
    const int*   chain_nb = (const int*)d_in[2];
    const float* pos      = (const float*)d_in[3];
    const float* maskA    = (const float*)d_in[4];
    const float* aa_emb   = (const float*)d_in[5];
    const float* rel_emb  = (const float*)d_in[6];
    const float* distcoef = (const float*)d_in[7];
    const float* dw1      = (const float*)d_in[8];
    const float* db1      = (const float*)d_in[9];
    const float* dw2      = (const float*)d_in[10];
    const float* db2      = (const float*)d_in[11];
    const float* ow1      = (const float*)d_in[12];
    const float* ob1      = (const float*)d_in[13];
    const float* ow2      = (const float*)d_in[14];
    const float* ob2      = (const float*)d_in[15];
    const float* ow3      = (const float*)d_in[16];
    const float* ob3      = (const float*)d_in[17];
    float* ws  = (float*)d_ws;
    float* out = (float*)d_out;

    prep_sp<<<(NAA*ABD + 255)/256, 256, 0, stream>>>(distcoef, ws);
    prep_tab<<<NAA + 65, 128, 0, stream>>>(aa_emb, rel_emb, ow1, ob1, ws);
    prep_wt<<<400, 256, 0, stream>>>(dw1, dw2, ow1, ow2, ow3, ws);
    pair_main<<<NBATCH*LL*4, 256, 0, stream>>>(aa, res_nb, chain_nb, pos, maskA,
                                               db1, db2, ob2, ob3, ws, out);
}